// Round 1
// baseline (643.798 us; speedup 1.0000x reference)
//
#include <hip/hip_runtime.h>

namespace {

constexpr int kNIn = 128;
constexpr int kNRec = 128;

__device__ __forceinline__ float fcomp(const float4 f, int i) {
  switch (i & 3) {
    case 0: return f.x;
    case 1: return f.y;
    case 2: return f.z;
    default: return f.w;
  }
}

// Block: 256 threads. Thread tile 4 rows x 4 cols -> block tile 32 rows x 128 cols.
// GEMMs accumulate with sequential-k FMA (matches BLAS sgemm order) in fp32.
// Epilogue uses explicit IEEE intrinsics (no contraction) to mirror numpy ops.
__global__ __launch_bounds__(256, 4) void lif_fused(
    const float* __restrict__ x, const float* __restrict__ z,
    const float* __restrict__ v, const float* __restrict__ t,
    const float* __restrict__ w_in, const float* __restrict__ w_rec,
    float* __restrict__ out, int batch) {
  const int tid = threadIdx.x;
  const int tc = tid & 31;        // 32 col groups x 4 cols = 128 cols
  const int tr = tid >> 5;        // 8 row groups x 4 rows = 32 rows
  const int row0 = blockIdx.x * 32 + tr * 4;
  const int c0 = tc * 4;

  float acc1[4][4];  // x @ w_in
  float acc2[4][4];  // z @ w_rec
#pragma unroll
  for (int i = 0; i < 4; ++i)
#pragma unroll
    for (int c = 0; c < 4; ++c) {
      acc1[i][c] = 0.0f;
      acc2[i][c] = 0.0f;
    }

  const float4* __restrict__ x4 =
      reinterpret_cast<const float4*>(x) + (size_t)row0 * (kNIn / 4);
  const float4* __restrict__ z4 =
      reinterpret_cast<const float4*>(z) + (size_t)row0 * (kNRec / 4);
  const float4* __restrict__ wi4 = reinterpret_cast<const float4*>(w_in) + tc;
  const float4* __restrict__ wr4 = reinterpret_cast<const float4*>(w_rec) + tc;

  for (int kq = 0; kq < kNIn / 4; ++kq) {
    float4 ax[4], az[4];
#pragma unroll
    for (int i = 0; i < 4; ++i) {
      ax[i] = x4[(size_t)i * (kNIn / 4) + kq];
      az[i] = z4[(size_t)i * (kNRec / 4) + kq];
    }
#pragma unroll
    for (int kk = 0; kk < 4; ++kk) {
      const int k = kq * 4 + kk;
      const float4 bi = wi4[(size_t)k * (kNRec / 4)];
      const float4 br = wr4[(size_t)k * (kNRec / 4)];
#pragma unroll
      for (int i = 0; i < 4; ++i) {
        const float axv = fcomp(ax[i], kk);
        const float azv = fcomp(az[i], kk);
        acc1[i][0] = __fmaf_rn(axv, bi.x, acc1[i][0]);
        acc1[i][1] = __fmaf_rn(axv, bi.y, acc1[i][1]);
        acc1[i][2] = __fmaf_rn(axv, bi.z, acc1[i][2]);
        acc1[i][3] = __fmaf_rn(axv, bi.w, acc1[i][3]);
        acc2[i][0] = __fmaf_rn(azv, br.x, acc2[i][0]);
        acc2[i][1] = __fmaf_rn(azv, br.y, acc2[i][1]);
        acc2[i][2] = __fmaf_rn(azv, br.z, acc2[i][2]);
        acc2[i][3] = __fmaf_rn(azv, br.w, acc2[i][3]);
      }
    }
  }

  // decay**e table for e in [0,7], base = (float)0.95 exactly as numpy's
  // float32 power of the weakly-promoted python scalar; double intermediate
  // gives the correctly-rounded f32 value.
  float ptab[8];
  {
    double d = 1.0;
    const double base = (double)0.95f;
#pragma unroll
    for (int j = 0; j < 8; ++j) {
      ptab[j] = (float)d;
      d *= base;
    }
  }

  const size_t BN = (size_t)batch * kNRec;
  float* __restrict__ out_z = out;
  float* __restrict__ out_v = out + BN;
  float* __restrict__ out_t = out + 2 * BN;

#pragma unroll
  for (int i = 0; i < 4; ++i) {
    const size_t off = (size_t)(row0 + i) * kNRec + c0;
    const float4 vv = *reinterpret_cast<const float4*>(v + off);
    const float4 zz = *reinterpret_cast<const float4*>(z + off);
    const float4 tt = *reinterpret_cast<const float4*>(t + off);
    float oz[4], ov[4], ot[4];
#pragma unroll
    for (int c = 0; c < 4; ++c) {
      const float s = __fadd_rn(acc1[i][c], acc2[i][c]);  // i_in = s1 + s2
      const bool h = (s != 0.0f);                         // h = (i_in != 0)
      const float tcur = fcomp(tt, c);
      // new_t = t + (h != 1)
      const float ntv = h ? tcur : __fadd_rn(tcur, 1.0f);
      const float vcur = fcomp(vv, c);
      const float zcur = fcomp(zz, c);
      // new_v = v * (1 - z)
      float nv = __fmul_rn(vcur, __fsub_rn(1.0f, zcur));
      // clamp below -1: new_v -= (1 - (v > -1)) * (v + 1)
      const float lp = (vcur > -1.0f) ? 1.0f : 0.0f;
      nv = __fsub_rn(nv, __fmul_rn(__fsub_rn(1.0f, lp), __fadd_rn(vcur, 1.0f)));
      // new_v *= decay ** (h * (new_t + 1))
      int ei = h ? (int)__fadd_rn(ntv, 1.0f) : 0;
      ei = ei < 0 ? 0 : (ei > 7 ? 7 : ei);
      nv = __fmul_rn(nv, ptab[ei]);
      // new_v += i_in
      nv = __fadd_rn(nv, s);
      // new_z = spike((new_v - THR)/THR): sign-equivalent to new_v > THR
      oz[c] = (nv > 0.4f) ? 1.0f : 0.0f;
      ov[c] = nv;
      // new_t *= (h != 1); new_t >= 0 so h-case gives +0 like numpy
      ot[c] = h ? 0.0f : ntv;
    }
    *reinterpret_cast<float4*>(out_z + off) = make_float4(oz[0], oz[1], oz[2], oz[3]);
    *reinterpret_cast<float4*>(out_v + off) = make_float4(ov[0], ov[1], ov[2], ov[3]);
    *reinterpret_cast<float4*>(out_t + off) = make_float4(ot[0], ot[1], ot[2], ot[3]);
  }
}

}  // namespace

extern "C" void kernel_launch(void* const* d_in, const int* in_sizes, int n_in,
                              void* d_out, int out_size, void* d_ws, size_t ws_size,
                              hipStream_t stream) {
  const float* x = (const float*)d_in[0];
  const float* z = (const float*)d_in[1];
  const float* v = (const float*)d_in[2];
  const float* t = (const float*)d_in[3];
  const float* w_in = (const float*)d_in[4];
  const float* w_rec = (const float*)d_in[5];
  float* out = (float*)d_out;

  const int batch = in_sizes[0] / kNIn;  // 131072
  const int blocks = batch / 32;         // 4096 blocks of 32 rows
  lif_fused<<<blocks, 256, 0, stream>>>(x, z, v, t, w_in, w_rec, out, batch);
}

// Round 2
// 519.618 us; speedup vs baseline: 1.2390x; 1.2390x over previous
//
#include <hip/hip_runtime.h>

namespace {

constexpr int kNIn = 128;
constexpr int kNRec = 128;
constexpr int BR = 64;              // rows per block
constexpr int KC = 32;              // k-chunk staged in LDS
constexpr int NCH = kNIn / KC;      // 4 chunks

typedef float vfloat4 __attribute__((ext_vector_type(4)));

__device__ __forceinline__ float fcomp(const float4 f, int i) {
  switch (i & 3) {
    case 0: return f.x;
    case 1: return f.y;
    case 2: return f.z;
    default: return f.w;
  }
}

__device__ __forceinline__ void nt_store4(float* p, float a, float b, float c,
                                          float d) {
  vfloat4 val = {a, b, c, d};
  __builtin_nontemporal_store(val, reinterpret_cast<vfloat4*>(p));
}

// Block: 256 threads, tile 64 rows x 128 cols; thread tile 4 rows x 8 cols
// (cols c0..c0+3 and c0+64..c0+67 so LDS weight reads are 16 contiguous
// lanes x 16B = 2-way bank aliasing = free).
// Weights staged in LDS in k-chunks of 32 (2 x 16 KB = 32 KB -> 5 blocks/CU).
// GEMM accumulates with sequential-k FMA in fp32 (merged x/z streams);
// epilogue uses explicit IEEE intrinsics to mirror numpy ops.
__global__ __launch_bounds__(256, 4) void lif_fused(
    const float* __restrict__ x, const float* __restrict__ z,
    const float* __restrict__ v, const float* __restrict__ t,
    const float* __restrict__ w_in, const float* __restrict__ w_rec,
    float* __restrict__ out, int batch) {
  __shared__ float swi[KC][kNRec];
  __shared__ float swr[KC][kNRec];

  const int tid = threadIdx.x;
  const int tc = tid & 15;          // 16 col groups
  const int tr = tid >> 4;          // 16 row groups x 4 rows = 64 rows
  const int row0 = blockIdx.x * BR + tr * 4;
  const int c0 = tc * 4;

  float acc[4][8];
#pragma unroll
  for (int i = 0; i < 4; ++i)
#pragma unroll
    for (int c = 0; c < 8; ++c) acc[i][c] = 0.0f;

  const float4* __restrict__ x4 =
      reinterpret_cast<const float4*>(x) + (size_t)row0 * (kNIn / 4);
  const float4* __restrict__ z4 =
      reinterpret_cast<const float4*>(z) + (size_t)row0 * (kNRec / 4);
  float4* swi4 = reinterpret_cast<float4*>(&swi[0][0]);
  float4* swr4 = reinterpret_cast<float4*>(&swr[0][0]);

  for (int ch = 0; ch < NCH; ++ch) {
    // Stage this chunk's weight rows (KC x 128 per matrix) into LDS.
    // Loads are issued before the chunk-open barrier so they fly during it.
    const float4* gwi =
        reinterpret_cast<const float4*>(w_in + (size_t)ch * KC * kNRec);
    const float4* gwr =
        reinterpret_cast<const float4*>(w_rec + (size_t)ch * KC * kNRec);
    float4 wa[4], wb[4];
#pragma unroll
    for (int j = 0; j < 4; ++j) {
      wa[j] = gwi[tid + 256 * j];
      wb[j] = gwr[tid + 256 * j];
    }
    if (ch) __syncthreads();  // prior chunk's readers must be done
#pragma unroll
    for (int j = 0; j < 4; ++j) {
      swi4[tid + 256 * j] = wa[j];
      swr4[tid + 256 * j] = wb[j];
    }
    __syncthreads();

#pragma unroll
    for (int kq = 0; kq < KC / 4; ++kq) {
      const int kg = ch * (KC / 4) + kq;  // global k-quad
      float4 ax[4], az[4];
#pragma unroll
      for (int i = 0; i < 4; ++i) {
        ax[i] = x4[(size_t)i * (kNIn / 4) + kg];
        az[i] = z4[(size_t)i * (kNRec / 4) + kg];
      }
#pragma unroll
      for (int kk = 0; kk < 4; ++kk) {
        const int k = kq * 4 + kk;
        const float4 wi0 = *reinterpret_cast<const float4*>(&swi[k][c0]);
        const float4 wi1 = *reinterpret_cast<const float4*>(&swi[k][c0 + 64]);
        const float4 wr0 = *reinterpret_cast<const float4*>(&swr[k][c0]);
        const float4 wr1 = *reinterpret_cast<const float4*>(&swr[k][c0 + 64]);
#pragma unroll
        for (int i = 0; i < 4; ++i) {
          const float a = fcomp(ax[i], kk);
          const float b = fcomp(az[i], kk);
          acc[i][0] = __fmaf_rn(a, wi0.x, acc[i][0]);
          acc[i][1] = __fmaf_rn(a, wi0.y, acc[i][1]);
          acc[i][2] = __fmaf_rn(a, wi0.z, acc[i][2]);
          acc[i][3] = __fmaf_rn(a, wi0.w, acc[i][3]);
          acc[i][4] = __fmaf_rn(a, wi1.x, acc[i][4]);
          acc[i][5] = __fmaf_rn(a, wi1.y, acc[i][5]);
          acc[i][6] = __fmaf_rn(a, wi1.z, acc[i][6]);
          acc[i][7] = __fmaf_rn(a, wi1.w, acc[i][7]);
          acc[i][0] = __fmaf_rn(b, wr0.x, acc[i][0]);
          acc[i][1] = __fmaf_rn(b, wr0.y, acc[i][1]);
          acc[i][2] = __fmaf_rn(b, wr0.z, acc[i][2]);
          acc[i][3] = __fmaf_rn(b, wr0.w, acc[i][3]);
          acc[i][4] = __fmaf_rn(b, wr1.x, acc[i][4]);
          acc[i][5] = __fmaf_rn(b, wr1.y, acc[i][5]);
          acc[i][6] = __fmaf_rn(b, wr1.z, acc[i][6]);
          acc[i][7] = __fmaf_rn(b, wr1.w, acc[i][7]);
        }
      }
    }
  }

  // decay**e table, e in [0,7]: t in [0,4] -> exponent new_t+1 <= 6.
  float ptab[8];
  {
    double d = 1.0;
    const double base = (double)0.95f;
#pragma unroll
    for (int j = 0; j < 8; ++j) {
      ptab[j] = (float)d;
      d *= base;
    }
  }

  const size_t BN = (size_t)batch * kNRec;
  float* __restrict__ out_z = out;
  float* __restrict__ out_v = out + BN;
  float* __restrict__ out_t = out + 2 * BN;

#pragma unroll
  for (int i = 0; i < 4; ++i) {
#pragma unroll
    for (int hlf = 0; hlf < 2; ++hlf) {
      const size_t off = (size_t)(row0 + i) * kNRec + c0 + hlf * 64;
      const float4 vv = *reinterpret_cast<const float4*>(v + off);
      const float4 zz = *reinterpret_cast<const float4*>(z + off);
      const float4 tt = *reinterpret_cast<const float4*>(t + off);
      float oz[4], ov[4], ot[4];
#pragma unroll
      for (int c = 0; c < 4; ++c) {
        const float s = acc[i][hlf * 4 + c];           // i_in
        const bool h = (s != 0.0f);                    // h = (i_in != 0)
        const float tcur = fcomp(tt, c);
        const float ntv = h ? tcur : __fadd_rn(tcur, 1.0f);  // new_t pre-reset
        const float vcur = fcomp(vv, c);
        const float zcur = fcomp(zz, c);
        // new_v = v * (1 - z)
        float nv = __fmul_rn(vcur, __fsub_rn(1.0f, zcur));
        // clamp below -1: new_v -= (1 - (v > -1)) * (v + 1)
        const float lp = (vcur > -1.0f) ? 1.0f : 0.0f;
        nv = __fsub_rn(nv,
                       __fmul_rn(__fsub_rn(1.0f, lp), __fadd_rn(vcur, 1.0f)));
        // new_v *= decay ** (h * (new_t + 1))
        int ei = h ? (int)__fadd_rn(ntv, 1.0f) : 0;
        ei = ei < 0 ? 0 : (ei > 7 ? 7 : ei);
        nv = __fmul_rn(nv, ptab[ei]);
        // new_v += i_in
        nv = __fadd_rn(nv, s);
        // new_z = spike((new_v - THR)/THR)  <=>  new_v > THR
        oz[c] = (nv > 0.4f) ? 1.0f : 0.0f;
        ov[c] = nv;
        ot[c] = h ? 0.0f : ntv;  // new_t *= (h != 1)
      }
      nt_store4(out_z + off, oz[0], oz[1], oz[2], oz[3]);
      nt_store4(out_v + off, ov[0], ov[1], ov[2], ov[3]);
      nt_store4(out_t + off, ot[0], ot[1], ot[2], ot[3]);
    }
  }
}

}  // namespace

extern "C" void kernel_launch(void* const* d_in, const int* in_sizes, int n_in,
                              void* d_out, int out_size, void* d_ws, size_t ws_size,
                              hipStream_t stream) {
  const float* x = (const float*)d_in[0];
  const float* z = (const float*)d_in[1];
  const float* v = (const float*)d_in[2];
  const float* t = (const float*)d_in[3];
  const float* w_in = (const float*)d_in[4];
  const float* w_rec = (const float*)d_in[5];
  float* out = (float*)d_out;

  const int batch = in_sizes[0] / kNIn;  // 131072
  const int blocks = batch / BR;         // 2048 blocks of 64 rows
  lif_fused<<<blocks, 256, 0, stream>>>(x, z, v, t, w_in, w_rec, out, batch);
}